// Round 10
// baseline (229.605 us; speedup 1.0000x reference)
//
#include <hip/hip_runtime.h>

#define DEVI static __device__ __forceinline__

typedef __attribute__((ext_vector_type(8))) short short8;
typedef __attribute__((ext_vector_type(4))) short short4v;
typedef __attribute__((ext_vector_type(4))) float f32x4;

DEVI float bf2f(short u) {
  union { unsigned u32; float f; } c;
  c.u32 = ((unsigned)(unsigned short)u) << 16;
  return c.f;
}
DEVI short f2bf(float f) {
  union { float f; unsigned u32; } c; c.f = f;
  unsigned x = c.u32;
  unsigned r = (x + 0x7FFFu + ((x >> 16) & 1u)) >> 16;
  return (short)(unsigned short)r;
}
DEVI float ex2(float x) {  // 2^x in one VALU op
  float r;
  asm("v_exp_f32 %0, %1" : "=v"(r) : "v"(x));
  return r;
}
DEVI unsigned cvtpk(float lo, float hi) {  // pack 2 f32 -> 2 bf16 (RNE)
  unsigned r;
  asm("v_cvt_pk_bf16_f32 %0, %1, %2" : "=v"(r) : "v"(lo), "v"(hi));
  return r;
}

DEVI void gload16(const void* g, void* l) {
  __builtin_amdgcn_global_load_lds(
      (__attribute__((address_space(1))) void*)(g),
      (__attribute__((address_space(3))) void*)(l), 16, 0, 0);
}

#define LOG2E 1.4426950408889634f
#define QSCALE 0.1275174470974102f   /* (1/sqrt(128)) * log2(e) */

// ---------------- merged prep: prep_x | sincos | wtrans --------------------
// blocks [0,4096): complexity+convert; [4096,4608): sincos; [4608,7680): wtrans
__global__ void prep_kernel(const float* __restrict__ x, short* __restrict__ xq,
                            short* __restrict__ xb, float* __restrict__ tsin,
                            float* __restrict__ tcos,
                            const float* __restrict__ Wq, const float* __restrict__ Wkv,
                            const float* __restrict__ Wo, short* __restrict__ T0,
                            short* __restrict__ T1, short* __restrict__ T2) {
  __shared__ float red[4];
  __shared__ __align__(16) short tile[64][68];
  const int bid = blockIdx.x, t = threadIdx.x;
  if (bid < 4096) {
    int row = bid;
    const float4* xr = (const float4*)(x + (size_t)row * 2048);
    float4 v0 = xr[t], v1 = xr[t + 256];
    float s = fabsf(v0.x) + fabsf(v0.y) + fabsf(v0.z) + fabsf(v0.w)
            + fabsf(v1.x) + fabsf(v1.y) + fabsf(v1.z) + fabsf(v1.w);
#pragma unroll
    for (int m = 1; m < 64; m <<= 1) s += __shfl_xor(s, m, 64);
    if ((t & 63) == 0) red[t >> 6] = s;
    __syncthreads();
    float tot = red[0] + red[1] + red[2] + red[3];
    float sc = 1.0f / (1.0f + expf(-tot));
    short4v q0, q1, b0, b1;
    q0[0] = f2bf(v0.x * sc); q0[1] = f2bf(v0.y * sc); q0[2] = f2bf(v0.z * sc); q0[3] = f2bf(v0.w * sc);
    q1[0] = f2bf(v1.x * sc); q1[1] = f2bf(v1.y * sc); q1[2] = f2bf(v1.z * sc); q1[3] = f2bf(v1.w * sc);
    b0[0] = f2bf(v0.x); b0[1] = f2bf(v0.y); b0[2] = f2bf(v0.z); b0[3] = f2bf(v0.w);
    b1[0] = f2bf(v1.x); b1[1] = f2bf(v1.y); b1[2] = f2bf(v1.z); b1[3] = f2bf(v1.w);
    size_t base = (size_t)row * 512;
    ((short4v*)xq)[base + t]       = q0;
    ((short4v*)xq)[base + t + 256] = q1;
    ((short4v*)xb)[base + t]       = b0;
    ((short4v*)xb)[base + t + 256] = b1;
  } else if (bid < 4608) {
    int idx = (bid - 4096) * 256 + t;   // 131072, d-major [64][2048]
    int d = idx >> 11, s2 = idx & 2047;
    float freq = powf(10000.0f, -(float)d / 64.0f);
    float f = (float)s2 * freq;
    tsin[idx] = sinf(f);
    tcos[idx] = cosf(f);
  } else {
    int wt = bid - 4608;
    const float* W = (wt < 1024) ? Wq : (wt < 2048 ? Wkv : Wo);
    short* WT      = (wt < 1024) ? T0 : (wt < 2048 ? T1 : T2);
    int n0 = (wt & 31) * 64, k0 = ((wt >> 5) & 31) * 64;
    int tr = t >> 4, tc = t & 15;
#pragma unroll
    for (int p = 0; p < 4; ++p) {
      int r = p * 16 + tr;        // k-local
      int c = tc * 4;             // n-local
      float4 v = *(const float4*)&W[(size_t)(k0 + r) * 2048 + n0 + c];
      tile[c + 0][r] = f2bf(v.x);
      tile[c + 1][r] = f2bf(v.y);
      tile[c + 2][r] = f2bf(v.z);
      tile[c + 3][r] = f2bf(v.w);
    }
    __syncthreads();
#pragma unroll
    for (int p = 0; p < 4; ++p) {
      int n = p * 16 + tr;
      int c = tc * 4;             // k-local
      *(short4v*)&WT[(size_t)(n0 + n) * 2048 + k0 + c] = *(const short4v*)&tile[n][c];
    }
  }
}

// ---------------- GEMM core: 128x128, BK=64, dbuf counted-vmcnt ------------
// 4 row-slice waves (acc[2][8]); T2 XOR-swizzle both-sides; 2 barriers/tile;
// STAGE(t+1) in flight across compute (vmcnt(8), never 0 mid-loop).
DEVI void gemm_core(const short* __restrict__ A, const short* __restrict__ BT,
                    int K, int m0, int n0, int tid,
                    short* As0, short* As1, short* Bs0, short* Bs1,
                    f32x4 (&acc)[2][8]) {
  const int wid = tid >> 6, lane = tid & 63;
  const int l15 = lane & 15, l4 = lane >> 4;
  const int sw7 = l15 & 7;
  const int T = K >> 6;
  auto STAGE = [&](short* Asb, short* Bsb, int t) {
#pragma unroll
    for (int p = 0; p < 4; ++p) {
      int cid = p * 256 + tid;
      int row = cid >> 3, ch = cid & 7;
      int cole = (ch ^ (row & 7)) * 8;
      gload16(A + (size_t)(m0 + row) * K + t * 64 + cole, Asb + cid * 8);
      gload16(BT + (size_t)(n0 + row) * K + t * 64 + cole, Bsb + cid * 8);
    }
  };
  STAGE(As0, Bs0, 0);
  for (int t = 0; t < T; ++t) {
    short* Asc = (t & 1) ? As1 : As0;
    short* Bsc = (t & 1) ? Bs1 : Bs0;
    if (t + 1 < T) {
      STAGE((t & 1) ? As0 : As1, (t & 1) ? Bs0 : Bs1, t + 1);
      asm volatile("s_waitcnt vmcnt(8)" ::: "memory");   // tile t landed; t+1 in flight
    } else {
      asm volatile("s_waitcnt vmcnt(0)" ::: "memory");
    }
    __builtin_amdgcn_s_barrier();
#pragma unroll
    for (int kk = 0; kk < 2; ++kk) {
      const int cc = ((kk * 4 + l4) ^ sw7) * 8;
      short8 af0 = *(const short8*)&Asc[(wid * 32 + l15) * 64 + cc];
      short8 af1 = *(const short8*)&Asc[(wid * 32 + 16 + l15) * 64 + cc];
      short8 bf0 = *(const short8*)&Bsc[(0 * 16 + l15) * 64 + cc];
      short8 bf1 = *(const short8*)&Bsc[(1 * 16 + l15) * 64 + cc];
      short8 bf2 = *(const short8*)&Bsc[(2 * 16 + l15) * 64 + cc];
      short8 bf3 = *(const short8*)&Bsc[(3 * 16 + l15) * 64 + cc];
      __builtin_amdgcn_s_setprio(1);
      acc[0][0] = __builtin_amdgcn_mfma_f32_16x16x32_bf16(af0, bf0, acc[0][0], 0, 0, 0);
      acc[1][0] = __builtin_amdgcn_mfma_f32_16x16x32_bf16(af1, bf0, acc[1][0], 0, 0, 0);
      acc[0][1] = __builtin_amdgcn_mfma_f32_16x16x32_bf16(af0, bf1, acc[0][1], 0, 0, 0);
      acc[1][1] = __builtin_amdgcn_mfma_f32_16x16x32_bf16(af1, bf1, acc[1][1], 0, 0, 0);
      acc[0][2] = __builtin_amdgcn_mfma_f32_16x16x32_bf16(af0, bf2, acc[0][2], 0, 0, 0);
      acc[1][2] = __builtin_amdgcn_mfma_f32_16x16x32_bf16(af1, bf2, acc[1][2], 0, 0, 0);
      acc[0][3] = __builtin_amdgcn_mfma_f32_16x16x32_bf16(af0, bf3, acc[0][3], 0, 0, 0);
      acc[1][3] = __builtin_amdgcn_mfma_f32_16x16x32_bf16(af1, bf3, acc[1][3], 0, 0, 0);
      __builtin_amdgcn_s_setprio(0);
      bf0 = *(const short8*)&Bsc[(4 * 16 + l15) * 64 + cc];
      bf1 = *(const short8*)&Bsc[(5 * 16 + l15) * 64 + cc];
      bf2 = *(const short8*)&Bsc[(6 * 16 + l15) * 64 + cc];
      bf3 = *(const short8*)&Bsc[(7 * 16 + l15) * 64 + cc];
      __builtin_amdgcn_s_setprio(1);
      acc[0][4] = __builtin_amdgcn_mfma_f32_16x16x32_bf16(af0, bf0, acc[0][4], 0, 0, 0);
      acc[1][4] = __builtin_amdgcn_mfma_f32_16x16x32_bf16(af1, bf0, acc[1][4], 0, 0, 0);
      acc[0][5] = __builtin_amdgcn_mfma_f32_16x16x32_bf16(af0, bf1, acc[0][5], 0, 0, 0);
      acc[1][5] = __builtin_amdgcn_mfma_f32_16x16x32_bf16(af1, bf1, acc[1][5], 0, 0, 0);
      acc[0][6] = __builtin_amdgcn_mfma_f32_16x16x32_bf16(af0, bf2, acc[0][6], 0, 0, 0);
      acc[1][6] = __builtin_amdgcn_mfma_f32_16x16x32_bf16(af1, bf2, acc[1][6], 0, 0, 0);
      acc[0][7] = __builtin_amdgcn_mfma_f32_16x16x32_bf16(af0, bf3, acc[0][7], 0, 0, 0);
      acc[1][7] = __builtin_amdgcn_mfma_f32_16x16x32_bf16(af1, bf3, acc[1][7], 0, 0, 0);
      __builtin_amdgcn_s_setprio(0);
    }
    __builtin_amdgcn_s_barrier();   // all waves done with buf before next STAGE
  }
}

// ---------------- merged QKV projection GEMMs (z=0: q, z=1: kv) ------------
__launch_bounds__(256, 2)
__global__ void gemm_qkv_kernel(const short* __restrict__ xq, const short* __restrict__ WqT,
                                const short* __restrict__ xb, const short* __restrict__ WkvT,
                                short* __restrict__ qr, short* __restrict__ kr,
                                short* __restrict__ vt,
                                const float* __restrict__ tsin, const float* __restrict__ tcos) {
  __shared__ __align__(16) short As[2][128 * 64];
  __shared__ __align__(16) short Bs[2][128 * 64];
  const int which = blockIdx.z;
  const int tid = threadIdx.x;
  const int nb = gridDim.x * gridDim.y;
  const int orig = blockIdx.y * gridDim.x + blockIdx.x;
  const int swz = (orig & 7) * (nb >> 3) + (orig >> 3);
  const int m0 = (swz / gridDim.x) * 128, n0 = (swz % gridDim.x) * 128;
  const short* A  = which ? xb : xq;
  const short* BT = which ? WkvT : WqT;
  f32x4 acc[2][8] = {};
  gemm_core(A, BT, 2048, m0, n0, tid, &As[0][0], &As[1][0], &Bs[0][0], &Bs[1][0], acc);

  const int wid = tid >> 6, lane = tid & 63;
  const int l15 = lane & 15, l4 = lane >> 4;
  const int b = m0 >> 11;
  const int sb = (m0 & 2047) + wid * 32;
  if (which == 0) {
    const int h = n0 >> 7;
    const size_t obase = ((size_t)(b * 16 + h) * 2048 + sb) * 128;
#pragma unroll
    for (int mi = 0; mi < 2; ++mi) {
      int srel = sb + mi * 16 + l4 * 4;
#pragma unroll
      for (int ni = 0; ni < 4; ++ni) {
        int d = ni * 16 + l15;
        float4 sn = *(const float4*)&tsin[d * 2048 + srel];
        float4 cs = *(const float4*)&tcos[d * 2048 + srel];
#pragma unroll
        for (int r = 0; r < 4; ++r) {
          float x1 = acc[mi][ni][r], x2 = acc[mi][ni + 4][r];
          float snr = (&sn.x)[r], csr = (&cs.x)[r];
          size_t ro = obase + (size_t)(mi * 16 + l4 * 4 + r) * 128;
          qr[ro + d]      = f2bf((x1 * csr - x2 * snr) * QSCALE);
          qr[ro + d + 64] = f2bf((x1 * snr + x2 * csr) * QSCALE);
        }
      }
    }
  } else {
    if (n0 < 1024) {
      const int kvh = n0 >> 7;
      const size_t obase = ((size_t)(b * 8 + kvh) * 2048 + sb) * 128;
#pragma unroll
      for (int mi = 0; mi < 2; ++mi) {
        int srel = sb + mi * 16 + l4 * 4;
#pragma unroll
        for (int ni = 0; ni < 4; ++ni) {
          int d = ni * 16 + l15;
          float4 sn = *(const float4*)&tsin[d * 2048 + srel];
          float4 cs = *(const float4*)&tcos[d * 2048 + srel];
#pragma unroll
          for (int r = 0; r < 4; ++r) {
            float x1 = acc[mi][ni][r], x2 = acc[mi][ni + 4][r];
            float snr = (&sn.x)[r], csr = (&cs.x)[r];
            size_t ro = obase + (size_t)(mi * 16 + l4 * 4 + r) * 128;
            kr[ro + d]      = f2bf(x1 * csr - x2 * snr);
            kr[ro + d + 64] = f2bf(x1 * snr + x2 * csr);
          }
        }
      }
    } else {
      const int kvh = (n0 - 1024) >> 7;
      const size_t vb = (size_t)(b * 8 + kvh) * 128;
#pragma unroll
      for (int mi = 0; mi < 2; ++mi) {
        int srel = sb + mi * 16 + l4 * 4;
#pragma unroll
        for (int ni = 0; ni < 8; ++ni) {
          int d = ni * 16 + l15;
          uint2 w;
          w.x = cvtpk(acc[mi][ni][0], acc[mi][ni][1]);
          w.y = cvtpk(acc[mi][ni][2], acc[mi][ni][3]);
          *(uint2*)&vt[(vb + d) * 2048 + srel] = w;
        }
      }
    }
  }
}

// ---------------- output projection GEMM (f32 + bias) ----------------------
__launch_bounds__(256, 2)
__global__ void gemm_out_kernel(const short* __restrict__ A, const short* __restrict__ BT,
                                float* __restrict__ Cout, const float* __restrict__ bias) {
  __shared__ __align__(16) short As[2][128 * 64];
  __shared__ __align__(16) short Bs[2][128 * 64];
  const int tid = threadIdx.x;
  const int nb = gridDim.x * gridDim.y;
  const int orig = blockIdx.y * gridDim.x + blockIdx.x;
  const int swz = (orig & 7) * (nb >> 3) + (orig >> 3);
  const int m0 = (swz / gridDim.x) * 128, n0 = (swz % gridDim.x) * 128;
  f32x4 acc[2][8] = {};
  gemm_core(A, BT, 2048, m0, n0, tid, &As[0][0], &As[1][0], &Bs[0][0], &Bs[1][0], acc);
  const int wid = tid >> 6, lane = tid & 63;
  const int l15 = lane & 15, l4 = lane >> 4;
#pragma unroll
  for (int mi = 0; mi < 2; ++mi) {
#pragma unroll
    for (int ni = 0; ni < 8; ++ni) {
      int col = n0 + ni * 16 + l15;
      float badd = bias[col];
#pragma unroll
      for (int r = 0; r < 4; ++r) {
        int row = m0 + wid * 32 + mi * 16 + l4 * 4 + r;
        Cout[(size_t)row * 2048 + col] = acc[mi][ni][r] + badd;
      }
    }
  }
}

// ---------------- flash attention v7: kc-split softmax/PV interleave -------
// 512 blocks; XCD swizzle (T1): XCD owns 4 heads = 2 KV heads (L2-resident).
// 8 waves x 16 q-rows; swapped MFMA; scalar softmax; defer-max (T13).
// Softmax split at kc boundary: jj01 -> PL -> PV kc0 reads issued -> jj23
// VALU overlaps kc0 MFMAs -> PL -> PV kc1. (PL chunk algebra: pa[kc] chunk
// (kc*4+l4)^sw7 is written exactly by jj in {2kc, 2kc+1}.)
// Mask semantics (faithful to reference): keep qk iff |i-j|>256 && i>=64 && j>=64.
__launch_bounds__(512, 4)
__global__ void attn_kernel(const short* __restrict__ qr, const short* __restrict__ kr,
                            const short* __restrict__ vt, short* __restrict__ ob) {
  __shared__ __align__(16) short Ks[2][64 * 128];    // 2 x 16 KB
  __shared__ __align__(16) short Vs[2][128 * 64];    // 2 x 16 KB
  __shared__ __align__(16) short PL[8][16 * 64];     // 16 KB
  const int tid = threadIdx.x;
  const int wid = tid >> 6, lane = tid & 63;
  const int l15 = lane & 15, l4 = lane >> 4;
  const int sw7 = l15 & 7;
  const int l4h = l4 >> 1, l4l = l4 & 1;
  const int f = blockIdx.x + (blockIdx.y << 4) + (blockIdx.z << 8);
  const int swb = (f & 7) * 64 + (f >> 3);
  const int qt = swb & 15, h = (swb >> 4) & 15, b = swb >> 8;
  const int kh = h >> 1;
  const int qb = qt * 128;
  const int q0 = qb + wid * 16;
  const float slope2 = exp2f(-0.5f * (float)(h + 1)) * LOG2E;
  const size_t qbase = ((size_t)(b * 16 + h) * 2048 + q0) * 128;
  const size_t kbase = ((size_t)(b * 8 + kh) * 2048) * 128;
  const size_t vbase = ((size_t)(b * 8 + kh) * 128) * 2048;
  short* pl = PL[wid];

  short8 aq[4];
#pragma unroll
  for (int kk = 0; kk < 4; ++kk)
    aq[kk] = *(const short8*)&qr[qbase + (size_t)l15 * 128 + kk * 32 + l4 * 8];

  f32x4 o[8] = {};
  float m_run = -1e30f, l_run = 0.0f;
  const int iq = q0 + l15;

  int lo0, n0t, lo1, n1t;
  if (qt == 0)      { lo0 = 0;   n0t = 32;          lo1 = 0; n1t = 0; }
  else if (qt == 1) { lo0 = 384; n0t = 26;          lo1 = 0; n1t = 0; }
  else {
    lo0 = 64;        n0t = 2 * qt - 3;
    lo1 = qb + 256;  n1t = (28 - 2 * qt > 0) ? (28 - 2 * qt) : 0;
  }
  const int nt = n0t + n1t;
  auto KV0 = [&](int i) { return i < n0t ? lo0 + i * 64 : lo1 + (i - n0t) * 64; };

  auto STAGE = [&](int bi, int kv0) {
#pragma unroll
    for (int i2 = 0; i2 < 2; ++i2) {
      int cid = i2 * 512 + tid;
      int krow = cid >> 4, kch = cid & 15;
      gload16(kr + kbase + (size_t)(kv0 + krow) * 128 + ((kch ^ (krow & 7)) * 8),
              &Ks[bi][cid * 8]);
    }
#pragma unroll
    for (int i2 = 0; i2 < 2; ++i2) {
      int cid = i2 * 512 + tid;
      int vrow = cid >> 3, vch = cid & 7;
      gload16(vt + vbase + (size_t)vrow * 2048 + kv0 + ((vch ^ (vrow & 7)) * 8),
              &Vs[bi][cid * 8]);
    }
  };

  STAGE(0, KV0(0));
  __syncthreads();
  int cur = 0;

  for (int it = 0; it < nt; ++it) {
    const int kv0 = KV0(it);
    if (it + 1 < nt) STAGE(cur ^ 1, KV0(it + 1));

    int mode;
    if (q0 + 15 < 64 || kv0 == 0) mode = 3;
    else if (kv0 <= q0 - 320)     mode = 1;
    else if (kv0 >= q0 + 272)     mode = 2;
    else                          mode = 0;

    if (mode != 3) {
      f32x4 sc[4];
#pragma unroll
      for (int jj = 0; jj < 4; ++jj) sc[jj] = (f32x4){0.f, 0.f, 0.f, 0.f};
      __builtin_amdgcn_s_setprio(1);
#pragma unroll
      for (int kk = 0; kk < 4; ++kk) {
#pragma unroll
        for (int jj = 0; jj < 4; ++jj) {
          short8 bk = *(const short8*)&Ks[cur][(jj * 16 + l15) * 128 + (((kk * 4 + l4) ^ sw7) * 8)];
          sc[jj] = __builtin_amdgcn_mfma_f32_16x16x32_bf16(bk, aq[kk], sc[jj], 0, 0, 0);
        }
      }
      __builtin_amdgcn_s_setprio(0);
      float pm = -1e30f;
      const float dbase = (float)(iq - kv0 - l4 * 4);
      if (mode == 0) {
#pragma unroll
        for (int jj = 0; jj < 4; ++jj) {
          float dj = dbase - 16.0f * jj;
#pragma unroll
          for (int r = 0; r < 4; ++r) {
            float d = dj - (float)r;
            float ad = fabsf(d);
            float v = fmaf(-slope2, ad, sc[jj][r]);
            v = (ad > 256.0f) ? v : -1e9f;
            sc[jj][r] = v;
            pm = fmaxf(pm, v);
          }
        }
      } else {
        const float sl = (mode == 1) ? -slope2 : slope2;
#pragma unroll
        for (int jj = 0; jj < 4; ++jj) {
          float dj = dbase - 16.0f * jj;
#pragma unroll
          for (int r = 0; r < 4; ++r) {
            float v = fmaf(sl, dj - (float)r, sc[jj][r]);
            sc[jj][r] = v;
            pm = fmaxf(pm, v);
          }
        }
      }
      pm = fmaxf(pm, __shfl_xor(pm, 16, 64));
      pm = fmaxf(pm, __shfl_xor(pm, 32, 64));
      if (!__all(pm <= m_run + 8.0f)) {
        float mn = fmaxf(m_run, pm);
        float corr = ex2(m_run - mn);
        l_run *= corr;
#pragma unroll
        for (int dn = 0; dn < 8; ++dn)
#pragma unroll
          for (int r = 0; r < 4; ++r) o[dn][r] *= corr;
        m_run = mn;
      }
      // ---- softmax half 1 (jj=0,1) -> PL ----
      float psum = 0.0f;
#pragma unroll
      for (int jj = 0; jj < 2; ++jj) {
        float p0 = ex2(sc[jj][0] - m_run), p1 = ex2(sc[jj][1] - m_run);
        float p2 = ex2(sc[jj][2] - m_run), p3 = ex2(sc[jj][3] - m_run);
        psum += (p0 + p1) + (p2 + p3);
        uint2 w; w.x = cvtpk(p0, p1); w.y = cvtpk(p2, p3);
        *(uint2*)&pl[l15 * 64 + (((jj * 2 + l4h) ^ sw7) * 8) + l4l * 4] = w;
      }
      asm volatile("s_waitcnt lgkmcnt(0)" ::: "memory");
      __builtin_amdgcn_sched_barrier(0);
      // ---- PV kc=0 reads issued; softmax half 2 VALU overlaps ----
      short8 pa = *(const short8*)&pl[l15 * 64 + ((l4 ^ sw7) * 8)];
      short8 bv0[8];
#pragma unroll
      for (int dn = 0; dn < 8; ++dn)
        bv0[dn] = *(const short8*)&Vs[cur][(dn * 16 + l15) * 64 + ((l4 ^ sw7) * 8)];
      uint2 w2[2];
#pragma unroll
      for (int jj = 2; jj < 4; ++jj) {
        float p0 = ex2(sc[jj][0] - m_run), p1 = ex2(sc[jj][1] - m_run);
        float p2 = ex2(sc[jj][2] - m_run), p3 = ex2(sc[jj][3] - m_run);
        psum += (p0 + p1) + (p2 + p3);
        w2[jj - 2].x = cvtpk(p0, p1); w2[jj - 2].y = cvtpk(p2, p3);
      }
      __builtin_amdgcn_s_setprio(1);
#pragma unroll
      for (int dn = 0; dn < 8; ++dn)
        o[dn] = __builtin_amdgcn_mfma_f32_16x16x32_bf16(bv0[dn], pa, o[dn], 0, 0, 0);
      __builtin_amdgcn_s_setprio(0);
#pragma unroll
      for (int jj = 2; jj < 4; ++jj)
        *(uint2*)&pl[l15 * 64 + (((jj * 2 + l4h) ^ sw7) * 8) + l4l * 4] = w2[jj - 2];
      asm volatile("s_waitcnt lgkmcnt(0)" ::: "memory");
      __builtin_amdgcn_sched_barrier(0);
      pa = *(const short8*)&pl[l15 * 64 + (((4 + l4) ^ sw7) * 8)];
      __builtin_amdgcn_s_setprio(1);
#pragma unroll
      for (int dn = 0; dn < 8; ++dn) {
        short8 bv = *(const short8*)&Vs[cur][(dn * 16 + l15) * 64 + (((4 + l4) ^ sw7) * 8)];
        o[dn] = __builtin_amdgcn_mfma_f32_16x16x32_bf16(bv, pa, o[dn], 0, 0, 0);
      }
      __builtin_amdgcn_s_setprio(0);
      psum += __shfl_xor(psum, 16, 64);
      psum += __shfl_xor(psum, 32, 64);
      l_run += psum;
    } else {
      // all-masked tile: uniform P = 2^(-1e9 - m_run); corr-wipe recurrence
      // reproduces the reference's uniform-attention rows.
      float pm = -1e9f;
      if (!__all(pm <= m_run + 8.0f)) {
        float mn = fmaxf(m_run, pm);
        float corr = ex2(m_run - mn);
        l_run *= corr;
#pragma unroll
        for (int dn = 0; dn < 8; ++dn)
#pragma unroll
          for (int r = 0; r < 4; ++r) o[dn][r] *= corr;
        m_run = mn;
      }
      float pu = ex2(-1e9f - m_run);
      l_run += 64.0f * pu;
      unsigned uu = cvtpk(pu, pu);
      short8 pa;
      ((unsigned*)&pa)[0] = uu; ((unsigned*)&pa)[1] = uu;
      ((unsigned*)&pa)[2] = uu; ((unsigned*)&pa)[3] = uu;
      __builtin_amdgcn_s_setprio(1);
#pragma unroll
      for (int c = 0; c < 2; ++c) {
#pragma unroll
        for (int dn = 0; dn < 8; ++dn) {
          short8 bv = *(const short8*)&Vs[cur][(dn * 16 + l15) * 64 + (((c * 4 + l4) ^ sw7) * 8)];
          o[dn] = __builtin_amdgcn_mfma_f32_16x16x32_bf16(bv, pa, o[dn], 0, 0, 0);
        }
      }
      __builtin_amdgcn_s_setprio(0);
    }
    __syncthreads();
    cur ^= 1;
  }

  float inv = 1.0f / l_run;
  size_t rbase = ((size_t)(b * 2048 + iq) * 16 + h) * 128;
#pragma unroll
  for (int dn = 0; dn < 8; ++dn) {
    uint2 w;
    w.x = cvtpk(o[dn][0] * inv, o[dn][1] * inv);
    w.y = cvtpk(o[dn][2] * inv, o[dn][3] * inv);
    *(uint2*)&ob[rbase + dn * 16 + l4 * 4] = w;
  }
}

// ---------------------------------------------------------------------------
extern "C" void kernel_launch(void* const* d_in, const int* in_sizes, int n_in,
                              void* d_out, int out_size, void* d_ws, size_t ws_size,
                              hipStream_t stream) {
  const float* x   = (const float*)d_in[0];
  const float* Wq  = (const float*)d_in[1];
  const float* Wkv = (const float*)d_in[2];
  const float* Wo  = (const float*)d_in[3];
  const float* bo  = (const float*)d_in[4];
  float* out = (float*)d_out;

  char* ws = (char*)d_ws;
  size_t off = 0;
  auto alloc = [&](size_t bytes) -> void* {
    void* p = ws + off;
    off += (bytes + 255) & ~(size_t)255;
    return p;
  };
  float* tsin  = (float*)alloc(64 * 2048 * 4);
  float* tcos  = (float*)alloc(64 * 2048 * 4);
  short* WqT   = (short*)alloc((size_t)2048 * 2048 * 2);
  short* WkvT  = (short*)alloc((size_t)2048 * 2048 * 2);
  short* WoT   = (short*)alloc((size_t)2048 * 2048 * 2);
  short* xq    = (short*)alloc((size_t)4096 * 2048 * 2);
  short* xb    = (short*)alloc((size_t)4096 * 2048 * 2);
  short* qr    = (short*)alloc((size_t)2 * 16 * 2048 * 128 * 2);
  short* kr    = (short*)alloc((size_t)2 * 8 * 2048 * 128 * 2);
  short* vt    = (short*)alloc((size_t)2 * 8 * 2048 * 128 * 2);
  short* ob    = xq;   // xq dead after gemm_qkv; reuse for attention output

  prep_kernel<<<7680, 256, 0, stream>>>(x, xq, xb, tsin, tcos, Wq, Wkv, Wo, WqT, WkvT, WoT);
  gemm_qkv_kernel<<<dim3(16, 32, 2), 256, 0, stream>>>(xq, WqT, xb, WkvT, qr, kr, vt, tsin, tcos);
  attn_kernel<<<dim3(16, 16, 2), 512, 0, stream>>>(qr, kr, vt, ob);
  gemm_out_kernel<<<dim3(16, 32), 256, 0, stream>>>(ob, WoT, out, bo);
  (void)in_sizes; (void)n_in; (void)out_size; (void)ws_size;
}

// Round 11
// 220.243 us; speedup vs baseline: 1.0425x; 1.0425x over previous
//
#include <hip/hip_runtime.h>

#define DEVI static __device__ __forceinline__

typedef __attribute__((ext_vector_type(8))) short short8;
typedef __attribute__((ext_vector_type(4))) short short4v;
typedef __attribute__((ext_vector_type(4))) float f32x4;

DEVI float bf2f(short u) {
  union { unsigned u32; float f; } c;
  c.u32 = ((unsigned)(unsigned short)u) << 16;
  return c.f;
}
DEVI short f2bf(float f) {
  union { float f; unsigned u32; } c; c.f = f;
  unsigned x = c.u32;
  unsigned r = (x + 0x7FFFu + ((x >> 16) & 1u)) >> 16;
  return (short)(unsigned short)r;
}
DEVI float ex2(float x) {  // 2^x in one VALU op
  float r;
  asm("v_exp_f32 %0, %1" : "=v"(r) : "v"(x));
  return r;
}
DEVI unsigned cvtpk(float lo, float hi) {  // pack 2 f32 -> 2 bf16 (RNE)
  unsigned r;
  asm("v_cvt_pk_bf16_f32 %0, %1, %2" : "=v"(r) : "v"(lo), "v"(hi));
  return r;
}

DEVI void gload16(const void* g, void* l) {
  __builtin_amdgcn_global_load_lds(
      (__attribute__((address_space(1))) void*)(g),
      (__attribute__((address_space(3))) void*)(l), 16, 0, 0);
}

#define LOG2E 1.4426950408889634f
#define QSCALE 0.1275174470974102f   /* (1/sqrt(128)) * log2(e) */

// ---------------- merged prep: x->bf16 + scale | sincos | wtrans -----------
// blocks [0,4096): complexity scale + convert; [4096,4608): sincos;
// [4608,7680): wtrans. NOTE: (x*c)@W == c*(x@W) -- scale applied in GEMM
// epilogue, so only ONE bf16 copy of x is needed.
__global__ void prep_kernel(const float* __restrict__ x, short* __restrict__ xb,
                            float* __restrict__ scale, float* __restrict__ tsin,
                            float* __restrict__ tcos,
                            const float* __restrict__ Wq, const float* __restrict__ Wkv,
                            const float* __restrict__ Wo, short* __restrict__ T0,
                            short* __restrict__ T1, short* __restrict__ T2) {
  __shared__ float red[4];
  __shared__ __align__(16) short tile[64][68];
  const int bid = blockIdx.x, t = threadIdx.x;
  if (bid < 4096) {
    int row = bid;
    const float4* xr = (const float4*)(x + (size_t)row * 2048);
    float4 v0 = xr[t], v1 = xr[t + 256];
    float s = fabsf(v0.x) + fabsf(v0.y) + fabsf(v0.z) + fabsf(v0.w)
            + fabsf(v1.x) + fabsf(v1.y) + fabsf(v1.z) + fabsf(v1.w);
#pragma unroll
    for (int m = 1; m < 64; m <<= 1) s += __shfl_xor(s, m, 64);
    if ((t & 63) == 0) red[t >> 6] = s;
    __syncthreads();
    if (t == 0) {
      float tot = red[0] + red[1] + red[2] + red[3];
      scale[row] = 1.0f / (1.0f + expf(-tot));
    }
    short4v b0, b1;
    b0[0] = f2bf(v0.x); b0[1] = f2bf(v0.y); b0[2] = f2bf(v0.z); b0[3] = f2bf(v0.w);
    b1[0] = f2bf(v1.x); b1[1] = f2bf(v1.y); b1[2] = f2bf(v1.z); b1[3] = f2bf(v1.w);
    size_t base = (size_t)row * 512;
    ((short4v*)xb)[base + t]       = b0;
    ((short4v*)xb)[base + t + 256] = b1;
  } else if (bid < 4608) {
    int idx = (bid - 4096) * 256 + t;   // 131072, d-major [64][2048]
    int d = idx >> 11, s2 = idx & 2047;
    float freq = powf(10000.0f, -(float)d / 64.0f);
    float f = (float)s2 * freq;
    tsin[idx] = sinf(f);
    tcos[idx] = cosf(f);
  } else {
    int wt = bid - 4608;
    const float* W = (wt < 1024) ? Wq : (wt < 2048 ? Wkv : Wo);
    short* WT      = (wt < 1024) ? T0 : (wt < 2048 ? T1 : T2);
    int n0 = (wt & 31) * 64, k0 = ((wt >> 5) & 31) * 64;
    int tr = t >> 4, tc = t & 15;
#pragma unroll
    for (int p = 0; p < 4; ++p) {
      int r = p * 16 + tr;        // k-local
      int c = tc * 4;             // n-local
      float4 v = *(const float4*)&W[(size_t)(k0 + r) * 2048 + n0 + c];
      tile[c + 0][r] = f2bf(v.x);
      tile[c + 1][r] = f2bf(v.y);
      tile[c + 2][r] = f2bf(v.z);
      tile[c + 3][r] = f2bf(v.w);
    }
    __syncthreads();
#pragma unroll
    for (int p = 0; p < 4; ++p) {
      int n = p * 16 + tr;
      int c = tc * 4;             // k-local
      *(short4v*)&WT[(size_t)(n0 + n) * 2048 + k0 + c] = *(const short4v*)&tile[n][c];
    }
  }
}

// ---------------- GEMM core: 128x128, BK=64, dbuf counted-vmcnt ------------
// 4 row-slice waves (acc[2][8]); T2 XOR-swizzle both-sides; 2 barriers/tile;
// STAGE(t+1) in flight across compute (vmcnt(8), never 0 mid-loop).
DEVI void gemm_core(const short* __restrict__ A, const short* __restrict__ BT,
                    int K, int m0, int n0, int tid,
                    short* As0, short* As1, short* Bs0, short* Bs1,
                    f32x4 (&acc)[2][8]) {
  const int wid = tid >> 6, lane = tid & 63;
  const int l15 = lane & 15, l4 = lane >> 4;
  const int sw7 = l15 & 7;
  const int T = K >> 6;
  auto STAGE = [&](short* Asb, short* Bsb, int t) {
#pragma unroll
    for (int p = 0; p < 4; ++p) {
      int cid = p * 256 + tid;
      int row = cid >> 3, ch = cid & 7;
      int cole = (ch ^ (row & 7)) * 8;
      gload16(A + (size_t)(m0 + row) * K + t * 64 + cole, Asb + cid * 8);
      gload16(BT + (size_t)(n0 + row) * K + t * 64 + cole, Bsb + cid * 8);
    }
  };
  STAGE(As0, Bs0, 0);
  for (int t = 0; t < T; ++t) {
    short* Asc = (t & 1) ? As1 : As0;
    short* Bsc = (t & 1) ? Bs1 : Bs0;
    if (t + 1 < T) {
      STAGE((t & 1) ? As0 : As1, (t & 1) ? Bs0 : Bs1, t + 1);
      asm volatile("s_waitcnt vmcnt(8)" ::: "memory");   // tile t landed; t+1 in flight
    } else {
      asm volatile("s_waitcnt vmcnt(0)" ::: "memory");
    }
    __builtin_amdgcn_s_barrier();
#pragma unroll
    for (int kk = 0; kk < 2; ++kk) {
      const int cc = ((kk * 4 + l4) ^ sw7) * 8;
      short8 af0 = *(const short8*)&Asc[(wid * 32 + l15) * 64 + cc];
      short8 af1 = *(const short8*)&Asc[(wid * 32 + 16 + l15) * 64 + cc];
      short8 bf0 = *(const short8*)&Bsc[(0 * 16 + l15) * 64 + cc];
      short8 bf1 = *(const short8*)&Bsc[(1 * 16 + l15) * 64 + cc];
      short8 bf2 = *(const short8*)&Bsc[(2 * 16 + l15) * 64 + cc];
      short8 bf3 = *(const short8*)&Bsc[(3 * 16 + l15) * 64 + cc];
      __builtin_amdgcn_s_setprio(1);
      acc[0][0] = __builtin_amdgcn_mfma_f32_16x16x32_bf16(af0, bf0, acc[0][0], 0, 0, 0);
      acc[1][0] = __builtin_amdgcn_mfma_f32_16x16x32_bf16(af1, bf0, acc[1][0], 0, 0, 0);
      acc[0][1] = __builtin_amdgcn_mfma_f32_16x16x32_bf16(af0, bf1, acc[0][1], 0, 0, 0);
      acc[1][1] = __builtin_amdgcn_mfma_f32_16x16x32_bf16(af1, bf1, acc[1][1], 0, 0, 0);
      acc[0][2] = __builtin_amdgcn_mfma_f32_16x16x32_bf16(af0, bf2, acc[0][2], 0, 0, 0);
      acc[1][2] = __builtin_amdgcn_mfma_f32_16x16x32_bf16(af1, bf2, acc[1][2], 0, 0, 0);
      acc[0][3] = __builtin_amdgcn_mfma_f32_16x16x32_bf16(af0, bf3, acc[0][3], 0, 0, 0);
      acc[1][3] = __builtin_amdgcn_mfma_f32_16x16x32_bf16(af1, bf3, acc[1][3], 0, 0, 0);
      __builtin_amdgcn_s_setprio(0);
      bf0 = *(const short8*)&Bsc[(4 * 16 + l15) * 64 + cc];
      bf1 = *(const short8*)&Bsc[(5 * 16 + l15) * 64 + cc];
      bf2 = *(const short8*)&Bsc[(6 * 16 + l15) * 64 + cc];
      bf3 = *(const short8*)&Bsc[(7 * 16 + l15) * 64 + cc];
      __builtin_amdgcn_s_setprio(1);
      acc[0][4] = __builtin_amdgcn_mfma_f32_16x16x32_bf16(af0, bf0, acc[0][4], 0, 0, 0);
      acc[1][4] = __builtin_amdgcn_mfma_f32_16x16x32_bf16(af1, bf0, acc[1][4], 0, 0, 0);
      acc[0][5] = __builtin_amdgcn_mfma_f32_16x16x32_bf16(af0, bf1, acc[0][5], 0, 0, 0);
      acc[1][5] = __builtin_amdgcn_mfma_f32_16x16x32_bf16(af1, bf1, acc[1][5], 0, 0, 0);
      acc[0][6] = __builtin_amdgcn_mfma_f32_16x16x32_bf16(af0, bf2, acc[0][6], 0, 0, 0);
      acc[1][6] = __builtin_amdgcn_mfma_f32_16x16x32_bf16(af1, bf2, acc[1][6], 0, 0, 0);
      acc[0][7] = __builtin_amdgcn_mfma_f32_16x16x32_bf16(af0, bf3, acc[0][7], 0, 0, 0);
      acc[1][7] = __builtin_amdgcn_mfma_f32_16x16x32_bf16(af1, bf3, acc[1][7], 0, 0, 0);
      __builtin_amdgcn_s_setprio(0);
    }
    __builtin_amdgcn_s_barrier();   // all waves done with buf before next STAGE
  }
}

// ---------------- merged QKV projection GEMMs (z=0: q, z=1: kv) ------------
// Both slices read A=xb; z=0 applies the complexity scale in the epilogue.
__launch_bounds__(256, 2)
__global__ void gemm_qkv_kernel(const short* __restrict__ xb, const short* __restrict__ WqT,
                                const short* __restrict__ WkvT, const float* __restrict__ scale,
                                short* __restrict__ qr, short* __restrict__ kr,
                                short* __restrict__ vt,
                                const float* __restrict__ tsin, const float* __restrict__ tcos) {
  __shared__ __align__(16) short As[2][128 * 64];
  __shared__ __align__(16) short Bs[2][128 * 64];
  const int which = blockIdx.z;
  const int tid = threadIdx.x;
  const int nb = gridDim.x * gridDim.y;
  const int orig = blockIdx.y * gridDim.x + blockIdx.x;
  const int swz = (orig & 7) * (nb >> 3) + (orig >> 3);
  const int m0 = (swz / gridDim.x) * 128, n0 = (swz % gridDim.x) * 128;
  const short* BT = which ? WkvT : WqT;
  f32x4 acc[2][8] = {};
  gemm_core(xb, BT, 2048, m0, n0, tid, &As[0][0], &As[1][0], &Bs[0][0], &Bs[1][0], acc);

  const int wid = tid >> 6, lane = tid & 63;
  const int l15 = lane & 15, l4 = lane >> 4;
  const int b = m0 >> 11;
  const int sb = (m0 & 2047) + wid * 32;
  if (which == 0) {
    const int h = n0 >> 7;
    const size_t obase = ((size_t)(b * 16 + h) * 2048 + sb) * 128;
#pragma unroll
    for (int mi = 0; mi < 2; ++mi) {
      int srel = sb + mi * 16 + l4 * 4;
      float4 scv = *(const float4*)&scale[m0 + wid * 32 + mi * 16 + l4 * 4];
#pragma unroll
      for (int ni = 0; ni < 4; ++ni) {
        int d = ni * 16 + l15;
        float4 sn = *(const float4*)&tsin[d * 2048 + srel];
        float4 cs = *(const float4*)&tcos[d * 2048 + srel];
#pragma unroll
        for (int r = 0; r < 4; ++r) {
          float qs = QSCALE * (&scv.x)[r];      // complexity gate commuted: c*(x@Wq)
          float x1 = acc[mi][ni][r], x2 = acc[mi][ni + 4][r];
          float snr = (&sn.x)[r], csr = (&cs.x)[r];
          size_t ro = obase + (size_t)(mi * 16 + l4 * 4 + r) * 128;
          qr[ro + d]      = f2bf((x1 * csr - x2 * snr) * qs);
          qr[ro + d + 64] = f2bf((x1 * snr + x2 * csr) * qs);
        }
      }
    }
  } else {
    if (n0 < 1024) {
      const int kvh = n0 >> 7;
      const size_t obase = ((size_t)(b * 8 + kvh) * 2048 + sb) * 128;
#pragma unroll
      for (int mi = 0; mi < 2; ++mi) {
        int srel = sb + mi * 16 + l4 * 4;
#pragma unroll
        for (int ni = 0; ni < 4; ++ni) {
          int d = ni * 16 + l15;
          float4 sn = *(const float4*)&tsin[d * 2048 + srel];
          float4 cs = *(const float4*)&tcos[d * 2048 + srel];
#pragma unroll
          for (int r = 0; r < 4; ++r) {
            float x1 = acc[mi][ni][r], x2 = acc[mi][ni + 4][r];
            float snr = (&sn.x)[r], csr = (&cs.x)[r];
            size_t ro = obase + (size_t)(mi * 16 + l4 * 4 + r) * 128;
            kr[ro + d]      = f2bf(x1 * csr - x2 * snr);
            kr[ro + d + 64] = f2bf(x1 * snr + x2 * csr);
          }
        }
      }
    } else {
      const int kvh = (n0 - 1024) >> 7;
      const size_t vb = (size_t)(b * 8 + kvh) * 128;
#pragma unroll
      for (int mi = 0; mi < 2; ++mi) {
        int srel = sb + mi * 16 + l4 * 4;
#pragma unroll
        for (int ni = 0; ni < 8; ++ni) {
          int d = ni * 16 + l15;
          uint2 w;
          w.x = cvtpk(acc[mi][ni][0], acc[mi][ni][1]);
          w.y = cvtpk(acc[mi][ni][2], acc[mi][ni][3]);
          *(uint2*)&vt[(vb + d) * 2048 + srel] = w;
        }
      }
    }
  }
}

// ---------------- output projection GEMM (f32 + bias) ----------------------
__launch_bounds__(256, 2)
__global__ void gemm_out_kernel(const short* __restrict__ A, const short* __restrict__ BT,
                                float* __restrict__ Cout, const float* __restrict__ bias) {
  __shared__ __align__(16) short As[2][128 * 64];
  __shared__ __align__(16) short Bs[2][128 * 64];
  const int tid = threadIdx.x;
  const int nb = gridDim.x * gridDim.y;
  const int orig = blockIdx.y * gridDim.x + blockIdx.x;
  const int swz = (orig & 7) * (nb >> 3) + (orig >> 3);
  const int m0 = (swz / gridDim.x) * 128, n0 = (swz % gridDim.x) * 128;
  f32x4 acc[2][8] = {};
  gemm_core(A, BT, 2048, m0, n0, tid, &As[0][0], &As[1][0], &Bs[0][0], &Bs[1][0], acc);
  const int wid = tid >> 6, lane = tid & 63;
  const int l15 = lane & 15, l4 = lane >> 4;
#pragma unroll
  for (int mi = 0; mi < 2; ++mi) {
#pragma unroll
    for (int ni = 0; ni < 8; ++ni) {
      int col = n0 + ni * 16 + l15;
      float badd = bias[col];
#pragma unroll
      for (int r = 0; r < 4; ++r) {
        int row = m0 + wid * 32 + mi * 16 + l4 * 4 + r;
        Cout[(size_t)row * 2048 + col] = acc[mi][ni][r] + badd;
      }
    }
  }
}

// ---------------- flash attention v6: swapped-MFMA + XCD-local KV ----------
// (reverted from r10's kc-split, which spilled: WRITE_SIZE 17->28MB)
// 512 blocks; XCD swizzle (T1): XCD owns 4 heads = 2 KV heads (L2-resident).
// 8 waves x 16 q-rows; scalar softmax; defer-max (T13).
// Mask semantics (faithful to reference): keep qk iff |i-j|>256 && i>=64 && j>=64.
__launch_bounds__(512, 4)
__global__ void attn_kernel(const short* __restrict__ qr, const short* __restrict__ kr,
                            const short* __restrict__ vt, short* __restrict__ ob) {
  __shared__ __align__(16) short Ks[2][64 * 128];    // 2 x 16 KB
  __shared__ __align__(16) short Vs[2][128 * 64];    // 2 x 16 KB
  __shared__ __align__(16) short PL[8][16 * 64];     // 16 KB
  const int tid = threadIdx.x;
  const int wid = tid >> 6, lane = tid & 63;
  const int l15 = lane & 15, l4 = lane >> 4;
  const int sw7 = l15 & 7;
  const int l4h = l4 >> 1, l4l = l4 & 1;
  const int f = blockIdx.x + (blockIdx.y << 4) + (blockIdx.z << 8);
  const int swb = (f & 7) * 64 + (f >> 3);
  const int qt = swb & 15, h = (swb >> 4) & 15, b = swb >> 8;
  const int kh = h >> 1;
  const int qb = qt * 128;
  const int q0 = qb + wid * 16;
  const float slope2 = exp2f(-0.5f * (float)(h + 1)) * LOG2E;
  const size_t qbase = ((size_t)(b * 16 + h) * 2048 + q0) * 128;
  const size_t kbase = ((size_t)(b * 8 + kh) * 2048) * 128;
  const size_t vbase = ((size_t)(b * 8 + kh) * 128) * 2048;
  short* pl = PL[wid];

  short8 aq[4];
#pragma unroll
  for (int kk = 0; kk < 4; ++kk)
    aq[kk] = *(const short8*)&qr[qbase + (size_t)l15 * 128 + kk * 32 + l4 * 8];

  f32x4 o[8] = {};
  float m_run = -1e30f, l_run = 0.0f;
  const int iq = q0 + l15;

  int lo0, n0t, lo1, n1t;
  if (qt == 0)      { lo0 = 0;   n0t = 32;          lo1 = 0; n1t = 0; }
  else if (qt == 1) { lo0 = 384; n0t = 26;          lo1 = 0; n1t = 0; }
  else {
    lo0 = 64;        n0t = 2 * qt - 3;
    lo1 = qb + 256;  n1t = (28 - 2 * qt > 0) ? (28 - 2 * qt) : 0;
  }
  const int nt = n0t + n1t;
  auto KV0 = [&](int i) { return i < n0t ? lo0 + i * 64 : lo1 + (i - n0t) * 64; };

  auto STAGE = [&](int bi, int kv0) {
#pragma unroll
    for (int i2 = 0; i2 < 2; ++i2) {
      int cid = i2 * 512 + tid;
      int krow = cid >> 4, kch = cid & 15;
      gload16(kr + kbase + (size_t)(kv0 + krow) * 128 + ((kch ^ (krow & 7)) * 8),
              &Ks[bi][cid * 8]);
    }
#pragma unroll
    for (int i2 = 0; i2 < 2; ++i2) {
      int cid = i2 * 512 + tid;
      int vrow = cid >> 3, vch = cid & 7;
      gload16(vt + vbase + (size_t)vrow * 2048 + kv0 + ((vch ^ (vrow & 7)) * 8),
              &Vs[bi][cid * 8]);
    }
  };

  STAGE(0, KV0(0));
  __syncthreads();
  int cur = 0;

  for (int it = 0; it < nt; ++it) {
    const int kv0 = KV0(it);
    if (it + 1 < nt) STAGE(cur ^ 1, KV0(it + 1));

    int mode;
    if (q0 + 15 < 64 || kv0 == 0) mode = 3;
    else if (kv0 <= q0 - 320)     mode = 1;
    else if (kv0 >= q0 + 272)     mode = 2;
    else                          mode = 0;

    if (mode != 3) {
      f32x4 sc[4];
#pragma unroll
      for (int jj = 0; jj < 4; ++jj) sc[jj] = (f32x4){0.f, 0.f, 0.f, 0.f};
      __builtin_amdgcn_s_setprio(1);
#pragma unroll
      for (int kk = 0; kk < 4; ++kk) {
#pragma unroll
        for (int jj = 0; jj < 4; ++jj) {
          short8 bk = *(const short8*)&Ks[cur][(jj * 16 + l15) * 128 + (((kk * 4 + l4) ^ sw7) * 8)];
          sc[jj] = __builtin_amdgcn_mfma_f32_16x16x32_bf16(bk, aq[kk], sc[jj], 0, 0, 0);
        }
      }
      __builtin_amdgcn_s_setprio(0);
      float pm = -1e30f;
      const float dbase = (float)(iq - kv0 - l4 * 4);
      if (mode == 0) {
#pragma unroll
        for (int jj = 0; jj < 4; ++jj) {
          float dj = dbase - 16.0f * jj;
#pragma unroll
          for (int r = 0; r < 4; ++r) {
            float d = dj - (float)r;
            float ad = fabsf(d);
            float v = fmaf(-slope2, ad, sc[jj][r]);
            v = (ad > 256.0f) ? v : -1e9f;
            sc[jj][r] = v;
            pm = fmaxf(pm, v);
          }
        }
      } else {
        const float sl = (mode == 1) ? -slope2 : slope2;
#pragma unroll
        for (int jj = 0; jj < 4; ++jj) {
          float dj = dbase - 16.0f * jj;
#pragma unroll
          for (int r = 0; r < 4; ++r) {
            float v = fmaf(sl, dj - (float)r, sc[jj][r]);
            sc[jj][r] = v;
            pm = fmaxf(pm, v);
          }
        }
      }
      pm = fmaxf(pm, __shfl_xor(pm, 16, 64));
      pm = fmaxf(pm, __shfl_xor(pm, 32, 64));
      if (!__all(pm <= m_run + 8.0f)) {
        float mn = fmaxf(m_run, pm);
        float corr = ex2(m_run - mn);
        l_run *= corr;
#pragma unroll
        for (int dn = 0; dn < 8; ++dn)
#pragma unroll
          for (int r = 0; r < 4; ++r) o[dn][r] *= corr;
        m_run = mn;
      }
      float psum = 0.0f;
#pragma unroll
      for (int jj = 0; jj < 4; ++jj) {
        float p0 = ex2(sc[jj][0] - m_run);
        float p1 = ex2(sc[jj][1] - m_run);
        float p2 = ex2(sc[jj][2] - m_run);
        float p3 = ex2(sc[jj][3] - m_run);
        psum += (p0 + p1) + (p2 + p3);
        uint2 w; w.x = cvtpk(p0, p1); w.y = cvtpk(p2, p3);
        int ad = l15 * 64 + (((jj * 2 + l4h) ^ sw7) * 8) + l4l * 4;
        *(uint2*)&pl[ad] = w;
      }
      psum += __shfl_xor(psum, 16, 64);
      psum += __shfl_xor(psum, 32, 64);
      l_run += psum;
      asm volatile("s_waitcnt lgkmcnt(0)" ::: "memory");
      __builtin_amdgcn_sched_barrier(0);
      __builtin_amdgcn_s_setprio(1);
#pragma unroll
      for (int c = 0; c < 2; ++c) {
        short8 pa = *(const short8*)&pl[l15 * 64 + (((c * 4 + l4) ^ sw7) * 8)];
#pragma unroll
        for (int dn = 0; dn < 8; ++dn) {
          short8 bv = *(const short8*)&Vs[cur][(dn * 16 + l15) * 64 + (((c * 4 + l4) ^ sw7) * 8)];
          o[dn] = __builtin_amdgcn_mfma_f32_16x16x32_bf16(bv, pa, o[dn], 0, 0, 0);
        }
      }
      __builtin_amdgcn_s_setprio(0);
    } else {
      float pm = -1e9f;
      if (!__all(pm <= m_run + 8.0f)) {
        float mn = fmaxf(m_run, pm);
        float corr = ex2(m_run - mn);
        l_run *= corr;
#pragma unroll
        for (int dn = 0; dn < 8; ++dn)
#pragma unroll
          for (int r = 0; r < 4; ++r) o[dn][r] *= corr;
        m_run = mn;
      }
      float pu = ex2(-1e9f - m_run);
      l_run += 64.0f * pu;
      unsigned uu = cvtpk(pu, pu);
      short8 pa;
      ((unsigned*)&pa)[0] = uu; ((unsigned*)&pa)[1] = uu;
      ((unsigned*)&pa)[2] = uu; ((unsigned*)&pa)[3] = uu;
      __builtin_amdgcn_s_setprio(1);
#pragma unroll
      for (int c = 0; c < 2; ++c) {
#pragma unroll
        for (int dn = 0; dn < 8; ++dn) {
          short8 bv = *(const short8*)&Vs[cur][(dn * 16 + l15) * 64 + (((c * 4 + l4) ^ sw7) * 8)];
          o[dn] = __builtin_amdgcn_mfma_f32_16x16x32_bf16(bv, pa, o[dn], 0, 0, 0);
        }
      }
      __builtin_amdgcn_s_setprio(0);
    }
    __syncthreads();
    cur ^= 1;
  }

  float inv = 1.0f / l_run;
  size_t rbase = ((size_t)(b * 2048 + iq) * 16 + h) * 128;
#pragma unroll
  for (int dn = 0; dn < 8; ++dn) {
    uint2 w;
    w.x = cvtpk(o[dn][0] * inv, o[dn][1] * inv);
    w.y = cvtpk(o[dn][2] * inv, o[dn][3] * inv);
    *(uint2*)&ob[rbase + dn * 16 + l4 * 4] = w;
  }
}

// ---------------------------------------------------------------------------
extern "C" void kernel_launch(void* const* d_in, const int* in_sizes, int n_in,
                              void* d_out, int out_size, void* d_ws, size_t ws_size,
                              hipStream_t stream) {
  const float* x   = (const float*)d_in[0];
  const float* Wq  = (const float*)d_in[1];
  const float* Wkv = (const float*)d_in[2];
  const float* Wo  = (const float*)d_in[3];
  const float* bo  = (const float*)d_in[4];
  float* out = (float*)d_out;

  char* ws = (char*)d_ws;
  size_t off = 0;
  auto alloc = [&](size_t bytes) -> void* {
    void* p = ws + off;
    off += (bytes + 255) & ~(size_t)255;
    return p;
  };
  float* tsin  = (float*)alloc(64 * 2048 * 4);
  float* tcos  = (float*)alloc(64 * 2048 * 4);
  float* scale = (float*)alloc(4096 * 4);
  short* WqT   = (short*)alloc((size_t)2048 * 2048 * 2);
  short* WkvT  = (short*)alloc((size_t)2048 * 2048 * 2);
  short* WoT   = (short*)alloc((size_t)2048 * 2048 * 2);
  short* xb    = (short*)alloc((size_t)4096 * 2048 * 2);
  short* qr    = (short*)alloc((size_t)2 * 16 * 2048 * 128 * 2);
  short* kr    = (short*)alloc((size_t)2 * 8 * 2048 * 128 * 2);
  short* vt    = (short*)alloc((size_t)2 * 8 * 2048 * 128 * 2);
  short* ob    = xb;   // xb dead after gemm_qkv; reuse for attention output

  prep_kernel<<<7680, 256, 0, stream>>>(x, xb, scale, tsin, tcos, Wq, Wkv, Wo, WqT, WkvT, WoT);
  gemm_qkv_kernel<<<dim3(16, 32, 2), 256, 0, stream>>>(xb, WqT, WkvT, scale, qr, kr, vt, tsin, tcos);
  attn_kernel<<<dim3(16, 16, 2), 512, 0, stream>>>(qr, kr, vt, ob);
  gemm_out_kernel<<<dim3(16, 32), 256, 0, stream>>>(ob, WoT, out, bo);
  (void)in_sizes; (void)n_in; (void)out_size; (void)ws_size;
}